// Round 1
// baseline (104.046 us; speedup 1.0000x reference)
//
#include <hip/hip_runtime.h>

// Problem constants (from reference): A=5, B=2, K=5, C=13, H=W=256
constexpr int A_ = 5, B_ = 2, K_ = 5, C_ = 13, H_ = 256, W_ = 256;
constexpr int TILE = 32;
constexpr int REG = TILE + 1;            // 33 (tile + 1 halo for pass-2 taps)
constexpr int NPOS = REG * REG;          // 1089
constexpr int NTHREADS = 256;
constexpr int PPT = (NPOS + NTHREADS - 1) / NTHREADS; // 5 positions per thread

__global__ __launch_bounds__(NTHREADS)
void fafmimo_warp_kernel(const float* __restrict__ bevs,
                         const float* __restrict__ tm,
                         const int*   __restrict__ nat,
                         const int*   __restrict__ center_p,
                         float* __restrict__ out)
{
    const int tileIdx = blockIdx.x;      // 0..63 (8x8 tiles of 32x32)
    const int abk     = blockIdx.y;      // 0..49  == (a*B+b)*K + k
    const int a   = abk / (B_ * K_);
    const int rem = abk % (B_ * K_);
    const int b   = rem / K_;
    const int k   = rem % K_;

    const int center  = center_p[0];
    const int n_agent = nat[b * A_ + center];
    const bool masked = (a < n_agent) && ((a != center) || (k == K_ - 1));

    const int th0 = (tileIdx / (W_ / TILE)) * TILE;   // tile origin row
    const int tw0 = (tileIdx % (W_ / TILE)) * TILE;   // tile origin col

    const int tid = threadIdx.x;
    const int rr  = tid >> 3;            // output row within tile, 0..31
    const int cg  = (tid & 7) << 2;      // output col group (float4), 0..28

    const size_t imgBase = (size_t)abk * C_ * H_ * W_;
    const float* img = bevs + imgBase;
    float*       o   = out  + imgBase;

    if (!masked) {
        // straight copy of this tile for all channels (float4, coalesced)
        #pragma unroll
        for (int c = 0; c < C_; ++c) {
            const int off = c * H_ * W_ + (th0 + rr) * W_ + tw0 + cg;
            const float4 v = *reinterpret_cast<const float4*>(img + off);
            *reinterpret_cast<float4*>(o + off) = v;
        }
        return;
    }

    // --- per-image transform params ---
    // trans_mats shape (A,K,B,4,4): T[a,b,k] = trans_mats[a,k,b]
    const int tb = ((a * K_ + k) * B_ + b) * 16;
    const float t00 = tm[tb + 0], t01 = tm[tb + 1], t03 = tm[tb + 3];
    const float t10 = tm[tb + 4], t11 = tm[tb + 5], t13 = tm[tb + 7];

    // Pass-2 (translation) in pixel units: ix1 = w + dx, iy1 = h + dy
    // dx = x_t*W/2 = (4*T03/128)*128 = 4*T03 ; dy = -4*T13
    const float dx = 4.0f * t03;
    const float dy = -4.0f * t13;
    const float fxf = floorf(dx), fyf = floorf(dy);
    const int   fx = (int)fxf,    fy = (int)fyf;
    const float wx2 = dx - fxf,   wy2 = dy - fyf;
    const float w00 = (1.0f - wx2) * (1.0f - wy2);
    const float w01 = wx2 * (1.0f - wy2);
    const float w10 = (1.0f - wx2) * wy2;
    const float w11 = wx2 * wy2;

    // --- precompute pass-1 taps for the 33x33 S1 region (channel-independent) ---
    int   o0[PPT], o1[PPT], o2[PPT], o3[PPT];
    float q0[PPT], q1[PPT], q2[PPT], q3[PPT];
    #pragma unroll
    for (int it = 0; it < PPT; ++it) {
        const int p = tid + it * NTHREADS;
        const int pr = p / REG;
        const int pc = p - pr * REG;
        // S1 global integer pixel this position corresponds to
        const int gyp = th0 + fy + pr;
        const int gxp = tw0 + fx + pc;
        const bool inreg = (p < NPOS) &&
                           (gyp >= 0) && (gyp < H_) && (gxp >= 0) && (gxp < W_);
        // normalized coords at that pixel
        const float Xc = ((float)gxp + 0.5f) * (1.0f / 128.0f) - 1.0f;
        const float Yc = ((float)gyp + 0.5f) * (1.0f / 128.0f) - 1.0f;
        // rotation grid (translation column of theta_rot is zero)
        const float gx = t00 * Xc + t01 * Yc;
        const float gy = t10 * Xc + t11 * Yc;
        // to source pixel coords: ((g+1)*256 - 1)*0.5 = g*128 + 127.5
        const float ix = gx * 128.0f + 127.5f;
        const float iy = gy * 128.0f + 127.5f;
        const float x0f = floorf(ix), y0f = floorf(iy);
        const float wx = ix - x0f,    wy = iy - y0f;
        const int x0 = (int)x0f, y0 = (int)y0f;
        const int x1 = x0 + 1,   y1 = y0 + 1;
        const bool vx0 = (x0 >= 0) && (x0 < W_);
        const bool vx1 = (x1 >= 0) && (x1 < W_);
        const bool vy0 = (y0 >= 0) && (y0 < H_);
        const bool vy1 = (y1 >= 0) && (y1 < H_);
        const int cx0 = min(max(x0, 0), W_ - 1);
        const int cx1 = min(max(x1, 0), W_ - 1);
        const int cy0 = min(max(y0, 0), H_ - 1);
        const int cy1 = min(max(y1, 0), H_ - 1);
        o0[it] = cy0 * W_ + cx0;
        o1[it] = cy0 * W_ + cx1;
        o2[it] = cy1 * W_ + cx0;
        o3[it] = cy1 * W_ + cx1;
        const float m = inreg ? 1.0f : 0.0f;
        q0[it] = (1.0f - wx) * (1.0f - wy) * ((vx0 && vy0) ? m : 0.0f);
        q1[it] = wx * (1.0f - wy)          * ((vx1 && vy0) ? m : 0.0f);
        q2[it] = (1.0f - wx) * wy          * ((vx0 && vy1) ? m : 0.0f);
        q3[it] = wx * wy                   * ((vx1 && vy1) ? m : 0.0f);
    }

    __shared__ float lds[NPOS];

    for (int c = 0; c < C_; ++c) {
        const float* __restrict__ imgc = img + c * H_ * W_;
        // pass 1: fill S1 region into LDS
        #pragma unroll
        for (int it = 0; it < PPT; ++it) {
            const int p = tid + it * NTHREADS;
            if (p < NPOS) {
                lds[p] = q0[it] * imgc[o0[it]] + q1[it] * imgc[o1[it]]
                       + q2[it] * imgc[o2[it]] + q3[it] * imgc[o3[it]];
            }
        }
        __syncthreads();

        // pass 2: constant-weight 2x2 blend from LDS, 4 outputs per thread
        const float* Lr0 = lds + rr * REG + cg;
        const float* Lr1 = Lr0 + REG;
        const float l0 = Lr0[0], l1 = Lr0[1], l2 = Lr0[2], l3 = Lr0[3], l4 = Lr0[4];
        const float m0 = Lr1[0], m1 = Lr1[1], m2 = Lr1[2], m3 = Lr1[3], m4 = Lr1[4];
        float4 v;
        v.x = w00 * l0 + w01 * l1 + w10 * m0 + w11 * m1;
        v.y = w00 * l1 + w01 * l2 + w10 * m1 + w11 * m2;
        v.z = w00 * l2 + w01 * l3 + w10 * m2 + w11 * m3;
        v.w = w00 * l3 + w01 * l4 + w10 * m3 + w11 * m4;
        *reinterpret_cast<float4*>(o + c * H_ * W_ + (th0 + rr) * W_ + tw0 + cg) = v;
        __syncthreads();   // LDS reused next channel
    }
}

extern "C" void kernel_launch(void* const* d_in, const int* in_sizes, int n_in,
                              void* d_out, int out_size, void* d_ws, size_t ws_size,
                              hipStream_t stream) {
    const float* bevs   = (const float*)d_in[0];
    const float* tm     = (const float*)d_in[1];
    const int*   nat    = (const int*)d_in[2];
    const int*   center = (const int*)d_in[4];
    float* out = (float*)d_out;

    dim3 grid((H_ / TILE) * (W_ / TILE), A_ * B_ * K_);
    dim3 block(NTHREADS);
    fafmimo_warp_kernel<<<grid, block, 0, stream>>>(bevs, tm, nat, center, out);
}